// Round 7
// baseline (319.758 us; speedup 1.0000x reference)
//
#include <hip/hip_runtime.h>
#include <math.h>

// ---------------- problem constants ----------------
#define BATCH 16
#define IH 384
#define IW 512
#define C1 10
#define P1H 191    // pooled H after conv1(382) / 2
#define P1W 255    // pooled W after conv1(510) / 2
#define P1WP 256   // padded row stride (16B-aligned rows)
#define P1PLANE (P1H * P1WP)     // 48896
#define C2 16
#define H2 189
#define W2 253
#define W2P 254    // padded row stride (8B-aligned rows)
#define C2PLANE (H2 * W2P)       // 48006
#define C3 32
#define H3 187
#define W3 251
#define N3 (H3*W3)        // 46937
#define KP 128
#define NCAP 1536         // NMS kept-candidate capacity (>= 1152 rank bound)
#define NEGV (-1e30f)
#define TW 132            // LDS tile width (128 + 2 halo + 2 align pad)

// ---- weight repack: conv2/conv3 weights -> ci-major contiguous ----
__global__ void k_repack(const float* __restrict__ w2, const float* __restrict__ w3,
                         float* __restrict__ w2t, float* __restrict__ w3t) {
    int i = blockIdx.x * 256 + threadIdx.x;
    if (i < C2 * C1 * 9) {                       // 1440
        int k = i % 9, r = i / 9;
        int ci = r / C2, oc = r % C2;
        w2t[i] = w2[(oc * C1 + ci) * 9 + k];
    } else if (i < C2 * C1 * 9 + C3 * C2 * 9) {  // + 4608
        int j = i - C2 * C1 * 9;
        int k = j % 9, r = j / 9;
        int ci = r / C3, oc = r % C3;
        w3t[j] = w3[(oc * C2 + ci) * 9 + k];
    }
}

// ------------- kernel 1: conv1(3->10,3x3) + PReLU + maxpool2 -------------
// streaming input (no cross-block reuse) -> no LDS staging needed.
__global__ __launch_bounds__(256, 2) void k_conv1pool(
        const float* __restrict__ im, const float* __restrict__ w,
        const float* __restrict__ bia, const float* __restrict__ slope,
        float* __restrict__ outp) {
    int x = blockIdx.x * 16 + threadIdx.x;
    int y = blockIdx.y * 16 + threadIdx.y;
    int bb = blockIdx.z;
    if (x >= P1W || y >= P1H) return;

    float in[3][4][4];
    #pragma unroll
    for (int ci = 0; ci < 3; ++ci) {
        const float* p = im + (((size_t)bb * 3 + ci) * IH + 2 * y) * IW + 2 * x;
        #pragma unroll
        for (int r = 0; r < 4; ++r) {
            const float2* q = (const float2*)(p + (size_t)r * IW);  // 8B-aligned
            float2 a0 = q[0], a1 = q[1];
            in[ci][r][0] = a0.x; in[ci][r][1] = a0.y;
            in[ci][r][2] = a1.x; in[ci][r][3] = a1.y;
        }
    }
    #pragma unroll
    for (int ci = 0; ci < 3; ++ci)
        #pragma unroll
        for (int r = 0; r < 4; ++r)
            #pragma unroll
            for (int c = 0; c < 4; ++c)
                in[ci][r][c] = (in[ci][r][c] - 127.5f) * 0.0078125f;

    #pragma unroll
    for (int oc = 0; oc < C1; ++oc) {
        const float* wo = w + oc * 27;  // uniform -> scalar loads
        float bv = bia[oc], sv = slope[oc];
        float best = -INFINITY;
        #pragma unroll
        for (int py = 0; py < 2; ++py)
            #pragma unroll
            for (int px = 0; px < 2; ++px) {
                float acc = bv;
                #pragma unroll
                for (int ci = 0; ci < 3; ++ci)
                    #pragma unroll
                    for (int ky = 0; ky < 3; ++ky)
                        #pragma unroll
                        for (int kx = 0; kx < 3; ++kx)
                            acc += in[ci][py + ky][px + kx] * wo[(ci * 3 + ky) * 3 + kx];
                float v = acc > 0.f ? acc : sv * acc;   // PReLU then pool-max
                best = fmaxf(best, v);
            }
        outp[((size_t)bb * C1 + oc) * P1PLANE + (size_t)y * P1WP + x] = best;
    }
}

// ------------- kernel 2: conv2(10->16,3x3) + PReLU, LDS-staged -------------
// Block (64,4) covers 128x4 output px. Stage [10][6][132] input tile (31.7 KB)
// with bulk float4 loads (HBM latency paid once, ~8 loads/thread in flight),
// then the proven 2px x 16oc FMA loop reads float2 pairs from LDS.
__global__ __launch_bounds__(256, 2) void k_conv2(
        const float* __restrict__ inp, const float* __restrict__ w2t,
        const float* __restrict__ bia, const float* __restrict__ slope,
        float* __restrict__ outp) {
    __shared__ float tile[C1][6][TW];
    int tx = threadIdx.x, ty = threadIdx.y;
    int tid = ty * 64 + tx;
    int bx = blockIdx.x, by = blockIdx.y, bb = blockIdx.z;
    int xbase = bx * 128;

    // stage: 10 ci x 6 rows x 33 float4 (rows 16B-aligned: stride 256, base 128)
    {
        const float* g = inp + (size_t)bb * C1 * P1PLANE + (size_t)(by * 4) * P1WP + xbase;
        for (int q = tid; q < C1 * 6 * 33; q += 256) {
            int c4 = q % 33; int t = q / 33; int rr = t % 6; int ci = t / 6;
            float4 val = *(const float4*)(g + (size_t)ci * P1PLANE + (size_t)rr * P1WP + c4 * 4);
            *(float4*)&tile[ci][rr][c4 * 4] = val;
        }
    }
    __syncthreads();

    int x0 = xbase + tx * 2;
    int y  = by * 4 + ty;
    bool alive = (x0 < W2) && (y < H2);

    float a0[C2], a1[C2];
    #pragma unroll
    for (int oc = 0; oc < C2; ++oc) { a0[oc] = bia[oc]; a1[oc] = bia[oc]; }

    for (int ci = 0; ci < C1; ++ci) {
        float v[3][4];
        #pragma unroll
        for (int r = 0; r < 3; ++r) {
            float2 u0 = *(const float2*)&tile[ci][ty + r][tx * 2];
            float2 u1 = *(const float2*)&tile[ci][ty + r][tx * 2 + 2];
            v[r][0] = u0.x; v[r][1] = u0.y; v[r][2] = u1.x; v[r][3] = u1.y;
        }
        const float* wc = w2t + ci * (C2 * 9);
        #pragma unroll
        for (int oc = 0; oc < C2; ++oc) {
            const float* wo = wc + oc * 9;
            float s0 = a0[oc], s1 = a1[oc];
            #pragma unroll
            for (int ky = 0; ky < 3; ++ky)
                #pragma unroll
                for (int kx = 0; kx < 3; ++kx) {
                    float wv = wo[ky * 3 + kx];
                    s0 += v[ky][kx]     * wv;
                    s1 += v[ky][kx + 1] * wv;
                }
            a0[oc] = s0; a1[oc] = s1;
        }
    }
    if (alive) {
        bool px1 = (x0 + 1 < W2);
        #pragma unroll
        for (int oc = 0; oc < C2; ++oc) {
            float sl = slope[oc];
            float* o = outp + ((size_t)bb * C2 + oc) * C2PLANE + (size_t)y * W2P + x0;
            float u0 = a0[oc]; o[0] = u0 > 0.f ? u0 : sl * u0;
            if (px1) { float u1 = a1[oc]; o[1] = u1 > 0.f ? u1 : sl * u1; }
        }
    }
}

// ------------- kernel 3: conv3(16->32,3x3)+PReLU + heads, LDS-staged ----
// Stage [16][6][132] (50.7 KB, 3 blocks/CU) with float2 loads (stride 254 rows
// are 8B-aligned), then 2px x 32oc FMA loop from LDS. Pad-column garbage flows
// only into lanes whose results are discarded (x0+3 -> unstored s1).
__global__ __launch_bounds__(256, 2) void k_conv3heads(
        const float* __restrict__ inp, const float* __restrict__ w3t,
        const float* __restrict__ b3, const float* __restrict__ s3,
        const float* __restrict__ w41, const float* __restrict__ b41,
        const float* __restrict__ w42, const float* __restrict__ b42,
        float* __restrict__ scores, float4* __restrict__ regf) {
    __shared__ float tile[C2][6][TW];
    int tx = threadIdx.x, ty = threadIdx.y;
    int tid = ty * 64 + tx;
    int bx = blockIdx.x, by = blockIdx.y, bb = blockIdx.z;
    int xbase = bx * 128;

    // stage: 16 ci x 6 rows x 66 float2
    {
        const float* g = inp + (size_t)bb * C2 * C2PLANE + (size_t)(by * 4) * W2P + xbase;
        for (int q = tid; q < C2 * 6 * 66; q += 256) {
            int c2 = q % 66; int t = q / 66; int rr = t % 6; int ci = t / 6;
            float2 val = *(const float2*)(g + (size_t)ci * C2PLANE + (size_t)rr * W2P + c2 * 2);
            *(float2*)&tile[ci][rr][c2 * 2] = val;
        }
    }
    __syncthreads();

    int x0 = xbase + tx * 2;
    int y  = by * 4 + ty;
    bool alive = (x0 < W3) && (y < H3);

    float a0[C3], a1[C3];
    #pragma unroll
    for (int oc = 0; oc < C3; ++oc) { a0[oc] = b3[oc]; a1[oc] = b3[oc]; }

    for (int ci = 0; ci < C2; ++ci) {
        float v[3][4];
        #pragma unroll
        for (int r = 0; r < 3; ++r) {
            float2 u0 = *(const float2*)&tile[ci][ty + r][tx * 2];
            float2 u1 = *(const float2*)&tile[ci][ty + r][tx * 2 + 2];
            v[r][0] = u0.x; v[r][1] = u0.y; v[r][2] = u1.x; v[r][3] = u1.y;
        }
        const float* wc = w3t + ci * (C3 * 9);
        #pragma unroll
        for (int oc = 0; oc < C3; ++oc) {
            const float* wo = wc + oc * 9;
            float s0 = a0[oc], s1 = a1[oc];
            #pragma unroll
            for (int ky = 0; ky < 3; ++ky)
                #pragma unroll
                for (int kx = 0; kx < 3; ++kx) {
                    float wv = wo[ky * 3 + kx];
                    s0 += v[ky][kx]     * wv;
                    s1 += v[ky][kx + 1] * wv;
                }
            a0[oc] = s0; a1[oc] = s1;
        }
    }
    if (!alive) return;

    #pragma unroll
    for (int oc = 0; oc < C3; ++oc) {
        float u0 = a0[oc], u1 = a1[oc], sl = s3[oc];
        a0[oc] = u0 > 0.f ? u0 : sl * u0;
        a1[oc] = u1 > 0.f ? u1 : sl * u1;
    }

    float l00 = b41[0], l01 = b41[1], l10 = b41[0], l11 = b41[1];
    #pragma unroll
    for (int c = 0; c < C3; ++c) {
        float w0 = w41[c], w1 = w41[C3 + c];
        l00 += a0[c] * w0; l01 += a0[c] * w1;
        l10 += a1[c] * w0; l11 += a1[c] * w1;
    }
    float m0 = fmaxf(l00, l01), m1 = fmaxf(l10, l11);
    float p0 = expf(l01 - m0) / (expf(l00 - m0) + expf(l01 - m0));
    float p1 = expf(l11 - m1) / (expf(l10 - m1) + expf(l11 - m1));

    float r00 = b42[0], r01 = b42[1], r02 = b42[2], r03 = b42[3];
    float r10 = b42[0], r11 = b42[1], r12 = b42[2], r13 = b42[3];
    #pragma unroll
    for (int c = 0; c < C3; ++c) {
        float w0 = w42[c], w1 = w42[C3 + c], w2 = w42[2 * C3 + c], w3v = w42[3 * C3 + c];
        r00 += a0[c] * w0; r01 += a0[c] * w1; r02 += a0[c] * w2; r03 += a0[c] * w3v;
        r10 += a1[c] * w0; r11 += a1[c] * w1; r12 += a1[c] * w2; r13 += a1[c] * w3v;
    }

    size_t n0 = (size_t)bb * N3 + (size_t)y * W3 + x0;
    scores[n0] = (p0 >= 0.6f) ? p0 : NEGV;
    regf[n0]   = make_float4(r00, r01, r02, r03);
    if (x0 + 1 < W3) {
        scores[n0 + 1] = (p1 >= 0.6f) ? p1 : NEGV;
        regf[n0 + 1]   = make_float4(r10, r11, r12, r13);
    }
}

// ------------- kernel 4: per-image NMS + box refine (R4/R5-proven) -------------
__global__ __launch_bounds__(1024) void k_nms(
        const float* __restrict__ scores, const float4* __restrict__ regf,
        float* __restrict__ outp) {
    __shared__ int   hist[2048];
    __shared__ float cs[NCAP];
    __shared__ int   cc[NCAP];
    __shared__ float psk[KP];
    __shared__ int   pck[KP];
    __shared__ int   misc[2];    // 0: compact cursor, 1: cutoff bin

    int tid = threadIdx.x;
    int bb = blockIdx.x;
    const float* sc = scores + (size_t)bb * N3;

    for (int i = tid; i < 2048; i += 1024) hist[i] = 0;
    if (tid < 2) misc[tid] = 0;
    __syncthreads();

    for (int i = tid; i < N3; i += 1024) {
        float s = sc[i];
        if (s > 0.f) {
            int b = (int)((s - 0.6f) * 5120.f);
            b = b < 0 ? 0 : (b > 2047 ? 2047 : b);
            atomicAdd(&hist[b], 1);
        }
    }
    __syncthreads();

    if (tid < 64) {
        int part = 0;
        #pragma unroll 8
        for (int k = 0; k < 32; ++k) part += hist[tid * 32 + k];
        int suf = part;
        #pragma unroll
        for (int off = 1; off < 64; off <<= 1) {
            int o = __shfl_down(suf, off);
            suf += (tid + off < 64) ? o : 0;
        }
        int M = __shfl(suf, 0);
        int target = M < 1152 ? M : 1152;
        int base = suf - part;
        if (M > 0 && base < target && base + part >= target) {
            int acc = base, cb = tid * 32;
            for (int b = tid * 32 + 31; b >= tid * 32; --b) {
                acc += hist[b];
                if (acc >= target) { cb = b; break; }
            }
            misc[1] = cb;
        }
    }
    __syncthreads();
    int cutbin = misc[1];

    for (int i = tid; i < N3; i += 1024) {
        float s = sc[i];
        if (s > 0.f) {
            int b = (int)((s - 0.6f) * 5120.f);
            b = b < 0 ? 0 : (b > 2047 ? 2047 : b);
            if (b >= cutbin) {
                int pos = atomicAdd(&misc[0], 1);
                if (pos < NCAP) {
                    int cy = i / W3, cx = i - cy * W3;
                    cs[pos] = s;
                    cc[pos] = (cy << 16) | cx;
                }
            }
        }
    }
    __syncthreads();
    if (tid >= 64) return;

    int K = misc[0]; if (K > NCAP) K = NCAP;
    K = __builtin_amdgcn_readfirstlane(K);
    int lane = tid;

    float sreg[24]; int cxr[24], cyr[24];
    #pragma unroll
    for (int j = 0; j < 24; ++j) {
        int e = j * 64 + lane;
        bool v = e < K;
        float s = v ? cs[e] : -INFINITY;
        int c = v ? cc[e] : 0x7FFF7FFF;
        sreg[j] = s; cxr[j] = c & 0xffff; cyr[j] = c >> 16;
    }

    int np = 0, ppx = -10000, ppy = -10000;
    for (int t = 0; t < KP; ++t) {
        float bs = -INFINITY; int bc = 0x7FFFFFFF;
        #pragma unroll
        for (int j = 0; j < 24; ++j) {
            if (j * 64 < K) {
                if ((unsigned)(cxr[j] - ppx + 1) <= 2u &&
                    (unsigned)(cyr[j] - ppy + 1) <= 2u) sreg[j] = -INFINITY;
                float s = sreg[j]; int c = (cyr[j] << 16) | cxr[j];
                if (s > bs || (s == bs && c < bc)) { bs = s; bc = c; }
            }
        }
        #pragma unroll
        for (int off = 32; off; off >>= 1) {
            float os = __shfl_xor(bs, off);
            int   oc_ = __shfl_xor(bc, off);
            if (os > bs || (os == bs && oc_ < bc)) { bs = os; bc = oc_; }
        }
        if (bs < 0.f) break;
        if (lane == 0) { psk[t] = bs; pck[t] = bc; }
        np = t + 1;
        ppx = bc & 0xffff; ppy = bc >> 16;
    }

    for (int t = lane; t < KP; t += 64) {
        float* o = outp + ((size_t)bb * KP + t) * 5;
        if (t < np) {
            int c = pck[t]; float s = psk[t];
            int cx = c & 0xffff, cy = c >> 16;
            float x1 = (float)(2 * cx + 1),  y1 = (float)(2 * cy + 1);
            float x2 = (float)(2 * cx + 12), y2 = (float)(2 * cy + 12);
            float4 r = regf[(size_t)bb * N3 + (size_t)cy * W3 + cx];
            float q1 = x1 + r.x * 11.f, q2 = y1 + r.y * 11.f;   // w = h = 11
            float q3 = x2 + r.z * 11.f, q4 = y2 + r.w * 11.f;
            float rw = q3 - q1, rh = q4 - q2;
            float L = fmaxf(rw, rh);
            float nx1 = q1 + rw * 0.5f - L * 0.5f;
            float ny1 = q2 + rh * 0.5f - L * 0.5f;
            o[0] = nx1; o[1] = ny1; o[2] = nx1 + L; o[3] = ny1 + L; o[4] = s;
        } else {
            o[0] = 0.f; o[1] = 0.f; o[2] = 0.f; o[3] = 0.f; o[4] = 0.f;
        }
    }
}

// ---------------- launcher ----------------
extern "C" void kernel_launch(void* const* d_in, const int* in_sizes, int n_in,
                              void* d_out, int out_size, void* d_ws, size_t ws_size,
                              hipStream_t stream) {
    const float* im   = (const float*)d_in[0];
    const float* c1w  = (const float*)d_in[1];
    const float* c1b  = (const float*)d_in[2];
    const float* p1   = (const float*)d_in[3];
    const float* c2w  = (const float*)d_in[4];
    const float* c2b  = (const float*)d_in[5];
    const float* p2   = (const float*)d_in[6];
    const float* c3w  = (const float*)d_in[7];
    const float* c3b  = (const float*)d_in[8];
    const float* p3   = (const float*)d_in[9];
    const float* c41w = (const float*)d_in[10];
    const float* c41b = (const float*)d_in[11];
    const float* c42w = (const float*)d_in[12];
    const float* c42b = (const float*)d_in[13];

    float* ws = (float*)d_ws;
    // layout (floats):
    //   [0 .. 7,823,360)           pool1 (256-stride); reused after conv2:
    //       scores [0..750,992) + regf [750,992..3,754,960)
    //   [7,823,360 .. 20,112,896)  conv2 out (254-stride)
    //   [20,112,896 .. +6048)      w2t, w3t
    const size_t POOL1P = (size_t)BATCH * C1 * P1PLANE;   // 7,823,360
    const size_t CONV2P = (size_t)BATCH * C2 * C2PLANE;   // 12,289,536
    float*  pool1   = ws;
    float*  conv2b  = ws + POOL1P;
    float*  w2t     = ws + POOL1P + CONV2P;
    float*  w3t     = w2t + C2 * C1 * 9;
    float*  scoresb = ws;                                  // reuse region0
    float4* regfb   = (float4*)(ws + (size_t)BATCH * N3);  // 16B-aligned

    k_repack  <<<dim3(24), dim3(256), 0, stream>>>(c2w, c3w, w2t, w3t);
    k_conv1pool<<<dim3(16, 12, BATCH), dim3(16, 16), 0, stream>>>(im, c1w, c1b, p1, pool1);
    k_conv2   <<<dim3(2, 48, BATCH), dim3(64, 4), 0, stream>>>(pool1, w2t, c2b, p2, conv2b);
    k_conv3heads<<<dim3(2, 47, BATCH), dim3(64, 4), 0, stream>>>(conv2b, w3t, c3b, p3,
                                                                 c41w, c41b, c42w, c42b,
                                                                 scoresb, regfb);
    k_nms<<<dim3(BATCH), dim3(1024), 0, stream>>>(scoresb, regfb, (float*)d_out);
}